// Round 6
// baseline (537.356 us; speedup 1.0000x reference)
//
#include <hip/hip_runtime.h>
#include <math.h>

#define N_PIX 3136
#define C_DIM 192
#define HID_DIM 384
#define KNN 9
#define EPS_BN 1e-5f

typedef __attribute__((ext_vector_type(4))) float f32x4;
typedef __attribute__((ext_vector_type(8))) short s16x8;
typedef unsigned short u16;

// ---------------- workspace layout (float units) ----------------
// g2 overlays h+sq+h2 (all dead after k2; k4 runs after k2).
static const size_t OFF_H   = 0;            // h fp32: 12544*192            = 2,408,448
static const size_t OFF_SQ  = 2408448;      // sq: 12544
static const size_t OFF_H2  = 2420992;      // h2 u16 [hi192|lo192]: 2,408,448 f
static const size_t OFF_G2  = 0;            // g2 u16 12544*768 = 4,816,896 f (overlay, fits in 4,829,440)
static const size_t OFF_PBF = 4829440;      // P bf16 u16 12544*384 = 2,408,448 f
static const size_t OFF_QBF = 7237888;      // Q bf16 u16 12544*384 = 2,408,448 f
static const size_t OFF_WC2 = 9646336;      // wc2 u16 768*384 = 147,456 f
static const size_t OFF_W5  = 9793792;      // w5 u16 192*768 = 73,728 f
static const size_t OFF_CST = 9867520;      // 1536 f
static const size_t OFF_IDX = 9869056;      // 112,896 int
static const size_t OFF_PL  = 9981952;      // 12544*7*9 u64 = 1,580,544 f

__device__ inline u16 f2bf_rn(float x) {
    unsigned u = __float_as_uint(x);
    unsigned r = u + 0x7fffu + ((u >> 16) & 1u);
    return (u16)(r >> 16);
}
__device__ inline float bf2f(u16 v) { return __uint_as_float((unsigned)v << 16); }
__device__ inline void split2(float x, u16& hi, u16& lo) {
    hi = f2bf_rn(x);
    lo = f2bf_rn(x - bf2f(hi));
}

// ---------------- prep: wc2/w5 bf16 splits + BN scale/shift ----------------
__global__ void k_prep(const float* __restrict__ gcn_w, const float* __restrict__ fc2_w,
                       const float* __restrict__ bn1_g, const float* __restrict__ bn1_b,
                       const float* __restrict__ bn1_m, const float* __restrict__ bn1_v,
                       const float* __restrict__ bng_g, const float* __restrict__ bng_b,
                       const float* __restrict__ bng_m, const float* __restrict__ bng_v,
                       const float* __restrict__ bn2_g, const float* __restrict__ bn2_b,
                       const float* __restrict__ bn2_m, const float* __restrict__ bn2_v,
                       u16* __restrict__ wc2, u16* __restrict__ w5, float* __restrict__ cst)
{
    int t = blockIdx.x * 256 + threadIdx.x;
    if (t < 768 * 192) {
        int o = t / 192, c = t % 192;
        float v = (o < 384) ? gcn_w[o * 384 + c] - gcn_w[o * 384 + 192 + c]
                            : gcn_w[(o - 384) * 384 + 192 + c];
        u16 hi, lo; split2(v, hi, lo);
        wc2[(size_t)o * 384 + c] = hi;
        wc2[(size_t)o * 384 + 192 + c] = lo;
    } else if (t < 768 * 192 + 192 * 384) {
        int u = t - 768 * 192;
        int c = u / 384, k = u % 384;
        u16 hi, lo; split2(fc2_w[(size_t)c * 384 + k], hi, lo);
        w5[(size_t)c * 768 + k] = hi;
        w5[(size_t)c * 768 + 384 + k] = lo;
    } else if (t < 768 * 192 + 192 * 384 + 768) {
        int u = t - 768 * 192 - 192 * 384;
        if (u < 192) {
            float s = bn1_g[u] / sqrtf(bn1_v[u] + EPS_BN);
            cst[u] = s; cst[192 + u] = bn1_b[u] - bn1_m[u] * s;
        } else if (u < 576) {
            int ch = u - 192;
            float s = bng_g[ch] / sqrtf(bng_v[ch] + EPS_BN);
            cst[384 + ch] = s; cst[768 + ch] = bng_b[ch] - bng_m[ch] * s;
        } else {
            int ch = u - 576;
            float s = bn2_g[ch] / sqrtf(bn2_v[ch] + EPS_BN);
            cst[1152 + ch] = s; cst[1344 + ch] = bn2_b[ch] - bn2_m[ch] * s;
        }
    }
}

// ---------------- K1: h = bn1(xf @ fc1_w^T + fc1_b)  (fp32 VALU GEMM) ----------------
__global__ __launch_bounds__(256) void k1_fc1_bn1(
    const float* __restrict__ x, const float* __restrict__ w,
    const float* __restrict__ bias, const float* __restrict__ cst,
    float* __restrict__ h)
{
    __shared__ float As[32][64];
    __shared__ float Bs[32][64];
    int bx = blockIdx.x;
    int o0 = blockIdx.y * 64;
    int b  = bx / 49;
    int n0 = (bx % 49) * 64;
    const float* xb = x + (size_t)b * C_DIM * N_PIX;
    int t = threadIdx.x;
    int tx = t & 15, ty = t >> 4;
    float acc[4][4] = {};
    for (int kc = 0; kc < 6; ++kc) {
        #pragma unroll
        for (int p = 0; p < 2; ++p) {
            int idx = t + p * 256;
            int kk = idx >> 4, j4 = idx & 15;
            float4 v = *reinterpret_cast<const float4*>(xb + (size_t)(kc * 32 + kk) * N_PIX + n0 + j4 * 4);
            *reinterpret_cast<float4*>(&As[kk][j4 * 4]) = v;
        }
        #pragma unroll
        for (int p = 0; p < 2; ++p) {
            int idx = t + p * 256;
            int oo = idx >> 3, c4 = idx & 7;
            float4 v = *reinterpret_cast<const float4*>(w + (size_t)(o0 + oo) * C_DIM + kc * 32 + c4 * 4);
            Bs[c4 * 4 + 0][oo] = v.x; Bs[c4 * 4 + 1][oo] = v.y;
            Bs[c4 * 4 + 2][oo] = v.z; Bs[c4 * 4 + 3][oo] = v.w;
        }
        __syncthreads();
        #pragma unroll
        for (int kk = 0; kk < 32; ++kk) {
            float4 av = *reinterpret_cast<const float4*>(&As[kk][ty * 4]);
            float4 bv = *reinterpret_cast<const float4*>(&Bs[kk][tx * 4]);
            float a[4] = {av.x, av.y, av.z, av.w};
            float bb[4] = {bv.x, bv.y, bv.z, bv.w};
            #pragma unroll
            for (int i = 0; i < 4; ++i)
                #pragma unroll
                for (int j = 0; j < 4; ++j) acc[i][j] += a[i] * bb[j];
        }
        __syncthreads();
    }
    #pragma unroll
    for (int i = 0; i < 4; ++i) {
        int n = n0 + ty * 4 + i;
        size_t r = (size_t)b * N_PIX + n;
        float vals[4];
        #pragma unroll
        for (int j = 0; j < 4; ++j) {
            int o = o0 + tx * 4 + j;
            vals[j] = (acc[i][j] + bias[o]) * cst[o] + cst[192 + o];
        }
        *reinterpret_cast<float4*>(h + r * C_DIM + o0 + tx * 4) =
            make_float4(vals[0], vals[1], vals[2], vals[3]);
    }
}

// ---------------- K1b: sq[r] = sum_c h[r][c]^2 ----------------
__global__ __launch_bounds__(256) void k_sq(const float* __restrict__ h, float* __restrict__ sq)
{
    int r = blockIdx.x * 256 + threadIdx.x;
    const float* hr = h + (size_t)r * C_DIM;
    float s = 0.f;
    #pragma unroll
    for (int c = 0; c < C_DIM; c += 4) {
        float4 v = *reinterpret_cast<const float4*>(hr + c);
        s += v.x * v.x + v.y * v.y + v.z * v.z + v.w * v.w;
    }
    sq[r] = s;
}

// ---------------- K1c: split h into bf16 hi|lo ----------------
__global__ __launch_bounds__(256) void k_split(const float* __restrict__ h, u16* __restrict__ h2)
{
    int t = blockIdx.x * 256 + threadIdx.x;
    int base = t * 4;
    int r = base / C_DIM, c = base % C_DIM;
    float4 v = *reinterpret_cast<const float4*>(h + base);
    float f[4] = {v.x, v.y, v.z, v.w};
    u16* dst = h2 + (size_t)r * 384 + c;
    #pragma unroll
    for (int j = 0; j < 4; ++j) {
        u16 hi, lo; split2(f[j], hi, lo);
        dst[j] = hi; dst[192 + j] = lo;
    }
}

// ---------------- K3: MFMA pairwise-dist + partial top-9, NO LDS ----------------
// grid 4b*49strip*7mc = 1372 blocks, 256 thr (4 waves, n-split).
// Wave w: rows n0+16w..+15 (A-frags in regs, full K).
// m-step 32 (2 mq): B-frags straight from global; 24KB/step working set -> L1-shared by 4 waves.
__global__ __launch_bounds__(256) void k3_knn(
    const u16* __restrict__ h2, const float* __restrict__ sq,
    unsigned long long* __restrict__ pl)
{
    int bx    = blockIdx.x;
    int b     = bx / 343;
    int rem   = bx % 343;
    int strip = rem / 7;
    int mc    = rem % 7;
    int n0 = strip * 64;
    const u16*  hb  = h2 + (size_t)b * N_PIX * 384;
    const float* sqb = sq + (size_t)b * N_PIX;
    int t = threadIdx.x;
    int lane = t & 63, w = t >> 6;
    int col16 = lane & 15, g = lane >> 4;

    s16x8 a_hi[6], a_lo[6];
    {
        const u16* ar = hb + (size_t)(n0 + w * 16 + col16) * 384;
        #pragma unroll
        for (int ko = 0; ko < 6; ++ko) {
            a_hi[ko] = *reinterpret_cast<const s16x8*>(ar + ko * 32 + g * 8);
            a_lo[ko] = *reinterpret_cast<const s16x8*>(ar + 192 + ko * 32 + g * 8);
        }
    }

    unsigned long long cand[4][KNN];
    #pragma unroll
    for (int i = 0; i < 4; ++i)
        #pragma unroll
        for (int q = 0; q < KNN; ++q) cand[i][q] = ~0ull;
    float sqn[4];
    #pragma unroll
    for (int i = 0; i < 4; ++i) sqn[i] = sqb[n0 + w * 16 + g * 4 + i];

    for (int step = 0; step < 14; ++step) {
        int m0 = mc * 448 + step * 32;
        const u16* bb = hb + (size_t)(m0 + col16) * 384 + g * 8;
        f32x4 acc0 = {0.f, 0.f, 0.f, 0.f};
        f32x4 acc1 = {0.f, 0.f, 0.f, 0.f};
        #pragma unroll
        for (int ko = 0; ko < 6; ++ko) {
            s16x8 b0h = *reinterpret_cast<const s16x8*>(bb + ko * 32);
            s16x8 b0l = *reinterpret_cast<const s16x8*>(bb + 192 + ko * 32);
            s16x8 b1h = *reinterpret_cast<const s16x8*>(bb + 16 * 384 + ko * 32);
            s16x8 b1l = *reinterpret_cast<const s16x8*>(bb + 16 * 384 + 192 + ko * 32);
            acc0 = __builtin_amdgcn_mfma_f32_16x16x32_bf16(a_hi[ko], b0h, acc0, 0, 0, 0);
            acc0 = __builtin_amdgcn_mfma_f32_16x16x32_bf16(a_hi[ko], b0l, acc0, 0, 0, 0);
            acc0 = __builtin_amdgcn_mfma_f32_16x16x32_bf16(a_lo[ko], b0h, acc0, 0, 0, 0);
            acc1 = __builtin_amdgcn_mfma_f32_16x16x32_bf16(a_hi[ko], b1h, acc1, 0, 0, 0);
            acc1 = __builtin_amdgcn_mfma_f32_16x16x32_bf16(a_hi[ko], b1l, acc1, 0, 0, 0);
            acc1 = __builtin_amdgcn_mfma_f32_16x16x32_bf16(a_lo[ko], b1h, acc1, 0, 0, 0);
        }
        float sqm0 = sqb[m0 + col16];
        float sqm1 = sqb[m0 + 16 + col16];
        #pragma unroll
        for (int mq = 0; mq < 2; ++mq) {
            int m = m0 + mq * 16 + col16;
            float sqm = mq ? sqm1 : sqm0;
            #pragma unroll
            for (int i = 0; i < 4; ++i) {
                float dot = mq ? acc1[i] : acc0[i];
                float dist = (sqn[i] - 2.0f * dot) + sqm;
                unsigned u = __float_as_uint(dist);
                u = (u & 0x80000000u) ? ~u : (u | 0x80000000u);
                unsigned long long key = ((unsigned long long)u << 32) | (unsigned)m;
                if (key < cand[i][KNN - 1]) {
                    cand[i][KNN - 1] = key;
                    #pragma unroll
                    for (int q = KNN - 1; q > 0; --q) {
                        unsigned long long lo = cand[i][q - 1], hi = cand[i][q];
                        if (hi < lo) { cand[i][q - 1] = hi; cand[i][q] = lo; }
                    }
                }
            }
        }
    }

    #pragma unroll
    for (int i = 0; i < 4; ++i) {
        int n = n0 + w * 16 + g * 4 + i;
        size_t rowg = (size_t)b * N_PIX + n;
        for (int r = 0; r < KNN; ++r) {
            unsigned long long my = cand[i][0];
            unsigned long long gm = my;
            #pragma unroll
            for (int s = 1; s < 16; s <<= 1) {
                unsigned long long o = __shfl_xor(gm, s);
                if (o < gm) gm = o;
            }
            if (gm == my) {
                #pragma unroll
                for (int q = 0; q < KNN - 1; ++q) cand[i][q] = cand[i][q + 1];
                cand[i][KNN - 1] = ~0ull;
            }
            if (col16 == 0)
                pl[(rowg * 7 + mc) * KNN + r] = gm;
        }
    }
}

// ---------------- K3b: merge 7 sorted partial lists -> final idx ----------------
__global__ __launch_bounds__(256) void k3b_merge(
    const unsigned long long* __restrict__ pl, int* __restrict__ idxout)
{
    int r = blockIdx.x * 256 + threadIdx.x;
    const unsigned long long* base = pl + (size_t)r * 63;
    unsigned long long list[KNN];
    #pragma unroll
    for (int q = 0; q < KNN; ++q) list[q] = ~0ull;
    for (int c = 0; c < 63; ++c) {
        unsigned long long k = base[c];
        if (k < list[KNN - 1]) {
            list[KNN - 1] = k;
            #pragma unroll
            for (int q = KNN - 1; q > 0; --q) {
                unsigned long long lo = list[q - 1], hi = list[q];
                if (hi < lo) { list[q - 1] = hi; list[q] = lo; }
            }
        }
    }
    #pragma unroll
    for (int q = 0; q < KNN; ++q)
        idxout[(size_t)r * KNN + q] = (int)(list[q] & 0xffffffffu);
}

// ---------------- K2: P,Q = h @ Wc^T (+bias) -> bf16, MFMA, no LDS ----------------
// grid (196 rowtiles, 24 otiles of 32)
__global__ __launch_bounds__(256) void k2_pq(
    const u16* __restrict__ h2, const u16* __restrict__ wc2,
    const float* __restrict__ gcnb, u16* __restrict__ Pbf, u16* __restrict__ Qbf)
{
    int r0 = blockIdx.x * 64;
    int o0 = blockIdx.y * 32;
    int t = threadIdx.x, lane = t & 63, w = t >> 6;
    int col16 = lane & 15, g = lane >> 4;

    s16x8 a_hi[6], a_lo[6];
    {
        const u16* ar = h2 + (size_t)(r0 + w * 16 + col16) * 384;
        #pragma unroll
        for (int ko = 0; ko < 6; ++ko) {
            a_hi[ko] = *reinterpret_cast<const s16x8*>(ar + ko * 32 + g * 8);
            a_lo[ko] = *reinterpret_cast<const s16x8*>(ar + 192 + ko * 32 + g * 8);
        }
    }
    const u16* br = wc2 + (size_t)(o0 + col16) * 384 + g * 8;
    f32x4 acc0 = {0.f, 0.f, 0.f, 0.f};
    f32x4 acc1 = {0.f, 0.f, 0.f, 0.f};
    #pragma unroll
    for (int ko = 0; ko < 6; ++ko) {
        s16x8 b0h = *reinterpret_cast<const s16x8*>(br + ko * 32);
        s16x8 b0l = *reinterpret_cast<const s16x8*>(br + 192 + ko * 32);
        s16x8 b1h = *reinterpret_cast<const s16x8*>(br + 16 * 384 + ko * 32);
        s16x8 b1l = *reinterpret_cast<const s16x8*>(br + 16 * 384 + 192 + ko * 32);
        acc0 = __builtin_amdgcn_mfma_f32_16x16x32_bf16(a_hi[ko], b0h, acc0, 0, 0, 0);
        acc0 = __builtin_amdgcn_mfma_f32_16x16x32_bf16(a_hi[ko], b0l, acc0, 0, 0, 0);
        acc0 = __builtin_amdgcn_mfma_f32_16x16x32_bf16(a_lo[ko], b0h, acc0, 0, 0, 0);
        acc1 = __builtin_amdgcn_mfma_f32_16x16x32_bf16(a_hi[ko], b1h, acc1, 0, 0, 0);
        acc1 = __builtin_amdgcn_mfma_f32_16x16x32_bf16(a_hi[ko], b1l, acc1, 0, 0, 0);
        acc1 = __builtin_amdgcn_mfma_f32_16x16x32_bf16(a_lo[ko], b1h, acc1, 0, 0, 0);
    }
    bool isP = (o0 < HID_DIM);
    #pragma unroll
    for (int oq = 0; oq < 2; ++oq) {
        int o = o0 + oq * 16 + col16;
        float bias = isP ? gcnb[o] : 0.0f;
        #pragma unroll
        for (int i = 0; i < 4; ++i) {
            size_t r = (size_t)(r0 + w * 16 + g * 4 + i);
            float v = (oq ? acc1[i] : acc0[i]) + bias;
            u16 bv = f2bf_rn(v);
            if (isP) Pbf[r * 384 + o] = bv;
            else     Qbf[r * 384 + (o - HID_DIM)] = bv;
        }
    }
}

// ---------------- K4: g2 = split(gelu(bn_g(P + max_k Q[idx[k]]))) ----------------
__global__ __launch_bounds__(384) void k4_agg(
    const u16* __restrict__ Pbf, const u16* __restrict__ Qbf,
    const int* __restrict__ idx, const float* __restrict__ cst,
    u16* __restrict__ g2)
{
    int blk = blockIdx.x;
    int b = blk / N_PIX;
    size_t row = (size_t)blk;
    const int* id = idx + row * KNN;
    int o = threadIdx.x;
    const u16* Qb = Qbf + (size_t)b * N_PIX * 384;
    float v = -INFINITY;
    #pragma unroll
    for (int k = 0; k < KNN; ++k)
        v = fmaxf(v, bf2f(Qb[(size_t)id[k] * 384 + o]));
    float p = bf2f(Pbf[row * 384 + o]);
    float y = (p + v) * cst[384 + o] + cst[768 + o];
    float ge = 0.5f * y * (1.0f + erff(y * 0.70710678118654752f));
    u16 hi, lo; split2(ge, hi, lo);
    g2[row * 768 + o] = hi;
    g2[row * 768 + 384 + o] = lo;
}

// ---------------- K5: out = bn2(g @ fc2_w^T + fc2_b) + x, MFMA, no LDS ----------------
// grid (196, 6 ctiles of 32); K=384
__global__ __launch_bounds__(256) void k5_fc2_bn2(
    const u16* __restrict__ g2, const u16* __restrict__ w5,
    const float* __restrict__ fc2b, const float* __restrict__ cst,
    const float* __restrict__ x, float* __restrict__ out)
{
    int bx = blockIdx.x;
    int c0 = blockIdx.y * 32;
    int b  = bx / 49;
    int n0 = (bx % 49) * 64;
    int r0 = bx * 64;
    int t = threadIdx.x, lane = t & 63, w = t >> 6;
    int col16 = lane & 15, g = lane >> 4;

    const u16* ar = g2 + (size_t)(r0 + w * 16 + col16) * 768;
    const u16* br = w5 + (size_t)(c0 + col16) * 768 + g * 8;
    f32x4 acc0 = {0.f, 0.f, 0.f, 0.f};
    f32x4 acc1 = {0.f, 0.f, 0.f, 0.f};
    #pragma unroll
    for (int kh = 0; kh < 2; ++kh) {
        s16x8 a_hi[6], a_lo[6];
        #pragma unroll
        for (int ko = 0; ko < 6; ++ko) {
            a_hi[ko] = *reinterpret_cast<const s16x8*>(ar + (kh * 6 + ko) * 32 + g * 8);
            a_lo[ko] = *reinterpret_cast<const s16x8*>(ar + 384 + (kh * 6 + ko) * 32 + g * 8);
        }
        #pragma unroll
        for (int ko = 0; ko < 6; ++ko) {
            int kk = (kh * 6 + ko) * 32;
            s16x8 b0h = *reinterpret_cast<const s16x8*>(br + kk);
            s16x8 b0l = *reinterpret_cast<const s16x8*>(br + 384 + kk);
            s16x8 b1h = *reinterpret_cast<const s16x8*>(br + 16 * 768 + kk);
            s16x8 b1l = *reinterpret_cast<const s16x8*>(br + 16 * 768 + 384 + kk);
            acc0 = __builtin_amdgcn_mfma_f32_16x16x32_bf16(a_hi[ko], b0h, acc0, 0, 0, 0);
            acc0 = __builtin_amdgcn_mfma_f32_16x16x32_bf16(a_hi[ko], b0l, acc0, 0, 0, 0);
            acc0 = __builtin_amdgcn_mfma_f32_16x16x32_bf16(a_lo[ko], b0h, acc0, 0, 0, 0);
            acc1 = __builtin_amdgcn_mfma_f32_16x16x32_bf16(a_hi[ko], b1h, acc1, 0, 0, 0);
            acc1 = __builtin_amdgcn_mfma_f32_16x16x32_bf16(a_hi[ko], b1l, acc1, 0, 0, 0);
            acc1 = __builtin_amdgcn_mfma_f32_16x16x32_bf16(a_lo[ko], b1h, acc1, 0, 0, 0);
        }
    }
    #pragma unroll
    for (int oq = 0; oq < 2; ++oq) {
        int c = c0 + oq * 16 + col16;
        float s2 = cst[1152 + c], sh2 = cst[1344 + c], bz = fc2b[c];
        #pragma unroll
        for (int i = 0; i < 4; ++i) {
            int n = n0 + w * 16 + g * 4 + i;
            size_t a = (size_t)b * C_DIM * N_PIX + (size_t)c * N_PIX + n;
            float v = (oq ? acc1[i] : acc0[i]) + bz;
            out[a] = v * s2 + sh2 + x[a];
        }
    }
}

extern "C" void kernel_launch(void* const* d_in, const int* in_sizes, int n_in,
                              void* d_out, int out_size, void* d_ws, size_t ws_size,
                              hipStream_t stream)
{
    const float* x      = (const float*)d_in[0];
    const float* fc1_w  = (const float*)d_in[1];
    const float* fc1_b  = (const float*)d_in[2];
    const float* bn1_g  = (const float*)d_in[3];
    const float* bn1_b  = (const float*)d_in[4];
    const float* bn1_m  = (const float*)d_in[5];
    const float* bn1_v  = (const float*)d_in[6];
    const float* gcn_w  = (const float*)d_in[7];
    const float* gcn_b  = (const float*)d_in[8];
    const float* bng_g  = (const float*)d_in[9];
    const float* bng_b  = (const float*)d_in[10];
    const float* bng_m  = (const float*)d_in[11];
    const float* bng_v  = (const float*)d_in[12];
    const float* fc2_w  = (const float*)d_in[13];
    const float* fc2_b  = (const float*)d_in[14];
    const float* bn2_g  = (const float*)d_in[15];
    const float* bn2_b  = (const float*)d_in[16];
    const float* bn2_m  = (const float*)d_in[17];
    const float* bn2_v  = (const float*)d_in[18];
    float* out = (float*)d_out;

    float* ws  = (float*)d_ws;
    float* h   = ws + OFF_H;
    float* sq  = ws + OFF_SQ;
    u16*   h2  = (u16*)(ws + OFF_H2);
    u16*   g2  = (u16*)(ws + OFF_G2);
    u16*   Pbf = (u16*)(ws + OFF_PBF);
    u16*   Qbf = (u16*)(ws + OFF_QBF);
    u16*   wc2 = (u16*)(ws + OFF_WC2);
    u16*   w5  = (u16*)(ws + OFF_W5);
    float* cst = ws + OFF_CST;
    int*   idx = (int*)(ws + OFF_IDX);
    unsigned long long* pl = (unsigned long long*)(ws + OFF_PL);

    k_prep<<<867, 256, 0, stream>>>(gcn_w, fc2_w,
                                    bn1_g, bn1_b, bn1_m, bn1_v,
                                    bng_g, bng_b, bng_m, bng_v,
                                    bn2_g, bn2_b, bn2_m, bn2_v, wc2, w5, cst);
    k1_fc1_bn1<<<dim3(196, 3), 256, 0, stream>>>(x, fc1_w, fc1_b, cst, h);
    k_sq<<<49, 256, 0, stream>>>(h, sq);
    k_split<<<2352, 256, 0, stream>>>(h, h2);
    k3_knn<<<1372, 256, 0, stream>>>(h2, sq, pl);
    k3b_merge<<<49, 256, 0, stream>>>(pl, idx);
    k2_pq<<<dim3(196, 24), 256, 0, stream>>>(h2, wc2, gcn_b, Pbf, Qbf);
    k4_agg<<<12544, 384, 0, stream>>>(Pbf, Qbf, idx, cst, g2);
    k5_fc2_bn2<<<dim3(196, 6), 256, 0, stream>>>(g2, w5, fc2_b, cst, x, out);
}